// Round 4
// baseline (274.848 us; speedup 1.0000x reference)
//
#include <hip/hip_runtime.h>
#include <hip/hip_bf16.h>

#define S_LEN 2048
#define DMODEL 1024
#define NHEAD 16
#define DKEY 64

typedef __attribute__((ext_vector_type(8))) short bf16x8;
typedef __attribute__((ext_vector_type(4))) float f32x4;
typedef __attribute__((ext_vector_type(16))) float f32x16;

__device__ __forceinline__ short f2bf(float f) {
  union { float f; unsigned u; } a; a.f = f;
  unsigned u = a.u;
  u += 0x7fff + ((u >> 16) & 1);   // RTNE
  return (short)(u >> 16);
}
__device__ __forceinline__ unsigned pk2bf(float a, float b) {
  union { __hip_bfloat162 h; unsigned u; } c;
  c.h = __float22bfloat162_rn(float2{a, b});
  return c.u;
}
__device__ __forceinline__ void gl_lds16(const void* g, void* l) {
  __builtin_amdgcn_global_load_lds(
      (const __attribute__((address_space(1))) unsigned int*)g,
      (__attribute__((address_space(3))) unsigned int*)l, 16, 0, 0);
}
#define EX2(x) __builtin_amdgcn_exp2f(x)

// ---------------------------------------------------------------------------
// Kernel -1: X (q,k,v) fp32 -> bf16, elementwise. grid (4096, 3) x 256.
// ---------------------------------------------------------------------------
__global__ __launch_bounds__(256) void convert_x(
    const float* __restrict__ q, const float* __restrict__ k,
    const float* __restrict__ v, short* __restrict__ Xb) {
  const int z = blockIdx.y;
  const float* X = (z == 0) ? q : (z == 1) ? k : v;
  short* dst = Xb + (size_t)z * 4194304;
  const int i = (blockIdx.x * 256 + threadIdx.x) * 4;
  const float4 xv = *(const float4*)&X[i];
  uint2 o;
  o.x = pk2bf(xv.x, xv.y);
  o.y = pk2bf(xv.z, xv.w);
  *(uint2*)&dst[i] = o;
}

// ---------------------------------------------------------------------------
// Kernel 0: weight transpose+convert. W[k][n] f32 -> Wt[n][k] bf16, 4 weights.
// ---------------------------------------------------------------------------
__global__ __launch_bounds__(256) void convert_w(
    const float* __restrict__ Wq, const float* __restrict__ Wk,
    const float* __restrict__ Wv, const float* __restrict__ Wo,
    short* __restrict__ Wt) {
  __shared__ short T[64][72];
  const int z = blockIdx.z;
  const float* W = (z == 0) ? Wq : (z == 1) ? Wk : (z == 2) ? Wv : Wo;
  short* dst = Wt + (size_t)z * 1048576;
  const int k0 = blockIdx.x * 64, n0 = blockIdx.y * 64;
  const int t = threadIdx.x;
#pragma unroll
  for (int p = 0; p < 4; ++p) {
    const int r = p * 16 + (t >> 4), c = (t & 15) * 4;
    const float4 wv = *(const float4*)&W[(size_t)(k0 + r) * DMODEL + n0 + c];
    T[c + 0][r] = f2bf(wv.x);
    T[c + 1][r] = f2bf(wv.y);
    T[c + 2][r] = f2bf(wv.z);
    T[c + 3][r] = f2bf(wv.w);
  }
  __syncthreads();
  const int rr = t >> 2, cc = (t & 3) * 16;
  const bf16x8 x0 = *(const bf16x8*)&T[rr][cc];
  const bf16x8 x1 = *(const bf16x8*)&T[rr][cc + 8];
  short* d = dst + (size_t)(n0 + rr) * DMODEL + k0 + cc;
  *(bf16x8*)&d[0] = x0;
  *(bf16x8*)&d[8] = x1;
}

// ---------------------------------------------------------------------------
// Bf16 tile staging with bank-conflict-free XOR chunk swizzle.
// Each thread issues exactly 2 global_load_lds (vmcnt += 2 per call).
// ---------------------------------------------------------------------------
__device__ __forceinline__ void stage_tile32(const short* gbase, short (*tile)[32],
                                             int w, int lane) {
  const int row = lane >> 2;                          // 0..15 per issue
  const int g = ((lane & 3) ^ ((row >> 1) & 3)) * 8;  // swizzled global chunk
#pragma unroll
  for (int i = 0; i < 2; ++i) {
    const int r = w * 32 + i * 16 + row;
    gl_lds16(gbase + (size_t)r * DMODEL + g, &tile[w * 32 + i * 16][0]);
  }
}

// ---------------------------------------------------------------------------
// Kernel 1: QKV projection, 128x128 tile, BK=32, all-bf16, swizzled LDS.
// 3-deep ring pipeline with counted vmcnt. Q/K epilogue: f32 LDS transpose
// (2 half-passes), vectorized rope loads, coalesced 16B stores.
// z=0 Q (RoPE + exp2-domain scale -> [bh][s][dk]), z=1 K (RoPE), z=2 V^T.
// ---------------------------------------------------------------------------
__global__ __launch_bounds__(256) void gemm_qkv(
    const short* __restrict__ Xb, const short* __restrict__ Wt,
    const float* __restrict__ bq, const float* __restrict__ bk,
    const float* __restrict__ bv, const float* __restrict__ rope,
    short* __restrict__ Qw, short* __restrict__ Kw, short* __restrict__ Vw) {
  __shared__ char smem[49152];   // 3 ring buffers x (A 8KB + B 8KB)

  const int z = blockIdx.z;
  const short* X = Xb + (size_t)z * 4194304;
  const float* bias = (z == 0) ? bq : (z == 1) ? bk : bv;
  const short* Wz = Wt + (size_t)z * 1048576;

  const int m0 = blockIdx.x * 128, n0 = blockIdx.y * 128;
  const int t = threadIdx.x;
  const int lane = t & 63;
  const int w = t >> 6;
  const int quad = lane >> 4;
  const int l15 = lane & 15;
  const int wr = (w >> 1) * 64, wc = (w & 1) * 64;
  const int rswz = (quad ^ ((l15 >> 1) & 3)) * 8;  // frag-read swizzled offset

  const short* Abase = X + (size_t)m0 * DMODEL;
  const short* Bbase = Wz + (size_t)n0 * DMODEL;

  f32x4 acc[4][4] = {};

  // prologue: tiles 0 and 1 into ring slots 0,1
  stage_tile32(Abase + 0, (short(*)[32])(smem + 0), w, lane);
  stage_tile32(Bbase + 0, (short(*)[32])(smem + 8192), w, lane);
  stage_tile32(Abase + 32, (short(*)[32])(smem + 16384), w, lane);
  stage_tile32(Bbase + 32, (short(*)[32])(smem + 16384 + 8192), w, lane);

  unsigned oc = 0, on = 16384, of = 32768;   // cur / next / future offsets
  for (int it = 0; it < 32; ++it) {
    if (it < 30) {
      const int kt = (it + 2) * 32;
      stage_tile32(Abase + kt, (short(*)[32])(smem + of), w, lane);
      stage_tile32(Bbase + kt, (short(*)[32])(smem + of + 8192), w, lane);
    }
    if (it < 30)       asm volatile("s_waitcnt vmcnt(8)" ::: "memory");
    else if (it == 30) asm volatile("s_waitcnt vmcnt(4)" ::: "memory");
    else               asm volatile("s_waitcnt vmcnt(0)" ::: "memory");
    __builtin_amdgcn_s_barrier();
    short (*As)[32] = (short(*)[32])(smem + oc);
    short (*Bs)[32] = (short(*)[32])(smem + oc + 8192);
    bf16x8 bf[4], af[4];
#pragma unroll
    for (int nj = 0; nj < 4; ++nj)
      bf[nj] = *(const bf16x8*)&Bs[wc + nj * 16 + l15][rswz];
#pragma unroll
    for (int mi = 0; mi < 4; ++mi)
      af[mi] = *(const bf16x8*)&As[wr + mi * 16 + l15][rswz];
#pragma unroll
    for (int mi = 0; mi < 4; ++mi)
#pragma unroll
      for (int nj = 0; nj < 4; ++nj)
        acc[mi][nj] =
            __builtin_amdgcn_mfma_f32_16x16x32_bf16(af[mi], bf[nj], acc[mi][nj], 0, 0, 0);
    asm volatile("s_waitcnt lgkmcnt(0)" ::: "memory");
    __builtin_amdgcn_s_barrier();
    const unsigned tmp = oc; oc = on; on = of; of = tmp;
  }

  const int b = (m0 + wr) >> 11;
  const int sbase = (m0 + wr) & 2047;

  if (z == 2) {
    __syncthreads();
    short (*tr)[72] = (short(*)[72])(smem + w * 9216);
    const int h2 = (n0 + wc) >> 6;
#pragma unroll
    for (int nj = 0; nj < 4; ++nj) {
      const float bval = bias[n0 + wc + nj * 16 + l15];
#pragma unroll
      for (int ti = 0; ti < 4; ++ti)
#pragma unroll
        for (int r = 0; r < 4; ++r)
          tr[nj * 16 + l15][ti * 16 + quad * 4 + r] = f2bf(acc[ti][nj][r] + bval);
    }
    asm volatile("s_waitcnt lgkmcnt(0)" ::: "memory");
    const int bh2 = b * NHEAD + h2;
#pragma unroll
    for (int cc = 0; cc < 4; ++cc) {
      const int row = cc * 16 + (lane >> 2);
      const int c0 = (lane & 3) * 16;
      const bf16x8 x0 = *(const bf16x8*)&tr[row][c0];
      const bf16x8 x1 = *(const bf16x8*)&tr[row][c0 + 8];
      short* d = Vw + ((size_t)bh2 * DKEY + row) * S_LEN + sbase + c0;
      *(bf16x8*)&d[0] = x0;
      *(bf16x8*)&d[8] = x1;
    }
    return;
  }

  // ---- Q/K epilogue: f32 LDS transpose + vectorized rope + coalesced store
  short* outw = (z == 0) ? Qw : Kw;
  const float qs = (z == 0) ? 0.18033688011112042f : 1.0f;  // log2(e)/8 for Q
  const int h = (n0 + wc) >> 6;
  const int bh = b * NHEAD + h;
  float (*tqf)[33] = (float(*)[33])(smem + w * 8448);   // per-wave, 8448 B
#pragma unroll
  for (int half = 0; half < 2; ++half) {
    asm volatile("s_waitcnt lgkmcnt(0)" ::: "memory");   // WAR vs prev reads
#pragma unroll
    for (int nj2 = 0; nj2 < 2; ++nj2) {
      const int nj = half * 2 + nj2;
      const float bval = bias[n0 + wc + nj * 16 + l15];
#pragma unroll
      for (int ti = 0; ti < 4; ++ti)
#pragma unroll
        for (int r = 0; r < 4; ++r)
          tqf[ti * 16 + quad * 4 + r][nj2 * 16 + l15] =
              (acc[ti][nj][r] + bval) * qs;
    }
    asm volatile("s_waitcnt lgkmcnt(0)" ::: "memory");
    const int row = lane;                    // one s-row per lane
    float v[32];
#pragma unroll
    for (int i = 0; i < 8; ++i) {
      const float4 x = *(const float4*)&tqf[row][i * 4];
      v[i * 4 + 0] = x.x; v[i * 4 + 1] = x.y;
      v[i * 4 + 2] = x.z; v[i * 4 + 3] = x.w;
    }
    const int s = sbase + row;
    const float* rp = &rope[((size_t)b * S_LEN + s) * DKEY + half * 32];
    short* d = outw + ((size_t)bh * S_LEN + s) * DKEY + half * 32;
#pragma unroll
    for (int i = 0; i < 4; ++i) {            // 8 dk per i
      const float4 ra = *(const float4*)&rp[i * 8];
      const float4 rb = *(const float4*)&rp[i * 8 + 4];
      uint4 o;
      o.x = pk2bf(v[i*8+0]*ra.y - v[i*8+1]*ra.x, v[i*8+1]*ra.y + v[i*8+0]*ra.x);
      o.y = pk2bf(v[i*8+2]*ra.w - v[i*8+3]*ra.z, v[i*8+3]*ra.w + v[i*8+2]*ra.z);
      o.z = pk2bf(v[i*8+4]*rb.y - v[i*8+5]*rb.x, v[i*8+5]*rb.y + v[i*8+4]*rb.x);
      o.w = pk2bf(v[i*8+6]*rb.w - v[i*8+7]*rb.z, v[i*8+7]*rb.w + v[i*8+6]*rb.z);
      *(uint4*)&d[i * 8] = o;
    }
  }
}

// ---------------------------------------------------------------------------
// Kernel 2: causal flash attention, 32x32 MFMA + in-register softmax.
// 4 warps x 32 q-rows = 128 q/block; KVBLK=64 double-buffered in LDS with
// counted vmcnt. Swapped QK^T (A=K, B=Q) puts a full q-row in each lane ->
// softmax = tree-max + 1 shfl_xor(32); P rebuilt in-register as PV A-operand
// (16 pk2bf + 16 shfl + cndmask) -- no LDS round-trip. O stored via a
// once-per-pass padded LDS transpose. Pairing (c, 15-c) keeps blocks uniform.
// ---------------------------------------------------------------------------
__global__ __launch_bounds__(256, 2) void attn_kernel(
    const short* __restrict__ Qw, const short* __restrict__ Kw,
    const short* __restrict__ Vw, const float* __restrict__ v_mask,
    short* __restrict__ Ow) {
  __shared__ char smem[32768];   // Kt[2][64][64] 16KB + Vt[2][64][64] 16KB

  const int t = threadIdx.x;
  const int w = t >> 6;          // 0..3
  const int lane = t & 63;
  const int q5 = lane & 31;      // q-row within warp tile / d-lane for PV
  const int hi = lane >> 5;
  const int bh = blockIdx.y;
  const int b = bh >> 4;
  const int h = bh & 15;

  const short* Kbase = Kw + (size_t)bh * S_LEN * DKEY;
  const short* Vbase = Vw + (size_t)bh * DKEY * S_LEN;
  const float* vmb = v_mask + (size_t)b * S_LEN;

  const int sr0 = t >> 3;        // staging: 0..31 row per issue
  const int sch = t & 7;         // staging: chunk slot

  // strict all-ones v_mask check (fast path)
  int okm = 1;
  {
    const float4* vm4 = (const float4*)vmb;
#pragma unroll
    for (int i = 0; i < 8; ++i) {
      const float4 a = vm4[lane * 8 + i];
      okm &= (a.x == 1.0f) & (a.y == 1.0f) & (a.z == 1.0f) & (a.w == 1.0f);
    }
  }
  const bool vmall = __all(okm);

  for (int pass = 0; pass < 2; ++pass) {
    int c = blockIdx.x;                       // 0..15
    if (blockIdx.y & 16) c = 15 - c;          // co-resident balance
    if (pass) c = 15 - c;                     // pair (c, 15-c): 34 tiles total
    const int qb = c * 128;
    const int qrow = qb + w * 32 + q5;

    const short* Qp = Qw + ((size_t)bh * S_LEN + qrow) * DKEY;
    bf16x8 qf[4];
#pragma unroll
    for (int ks = 0; ks < 4; ++ks)
      qf[ks] = *(const bf16x8*)(Qp + ks * 16 + hi * 8);

    float m_i = -1.0e30f, l_i = 0.f;
    f32x16 acc0 = {}, acc1 = {};

    const int niter = 2 * c + 2;
    const int wlast = (qb + w * 32 + 31) >> 6;

    __syncthreads();   // protect LDS from previous pass epilogue reads
    // prologue: stage tile 0 into buf 0 (4 gl_lds per thread)
#pragma unroll
    for (int i = 0; i < 2; ++i) {
      const int row = i * 32 + sr0;
      const int g = sch ^ (row & 7);
      gl_lds16(Kbase + (size_t)row * DKEY + g * 8,
               smem + row * 128 + sch * 16);
      gl_lds16(Vbase + (size_t)row * S_LEN + g * 8,
               smem + 16384 + row * 128 + sch * 16);
    }

    int cur = 0;
    for (int it = 0; it < niter; ++it) {
      const int j0 = it * 64;
      if (it + 1 < niter) {   // prefetch next tile into buf^1
        const int jn = j0 + 64;
        char* kb = smem + (cur ^ 1) * 8192;
        char* vb = smem + 16384 + (cur ^ 1) * 8192;
#pragma unroll
        for (int i = 0; i < 2; ++i) {
          const int row = i * 32 + sr0;
          const int g = sch ^ (row & 7);
          gl_lds16(Kbase + (size_t)(jn + row) * DKEY + g * 8,
                   kb + row * 128 + sch * 16);
          gl_lds16(Vbase + (size_t)row * S_LEN + jn + g * 8,
                   vb + row * 128 + sch * 16);
        }
        asm volatile("s_waitcnt vmcnt(4)" ::: "memory");
      } else {
        asm volatile("s_waitcnt vmcnt(0)" ::: "memory");
      }
      __builtin_amdgcn_s_barrier();

      if (it <= wlast) {
        short (*Ktc)[64] = (short(*)[64])(smem + cur * 8192);
        short (*Vtc)[64] = (short(*)[64])(smem + 16384 + cur * 8192);
        const int swz = q5 & 7;

        // ---- QK^T: S[key][q], two 32-key halves
        f32x16 s0 = {}, s1 = {};
        __builtin_amdgcn_s_setprio(1);
#pragma unroll
        for (int ks = 0; ks < 4; ++ks) {
          const int sl = ((2 * ks + hi) ^ swz) * 8;
          const bf16x8 k0 = *(const bf16x8*)&Ktc[q5][sl];
          const bf16x8 k1 = *(const bf16x8*)&Ktc[32 + q5][sl];
          s0 = __builtin_amdgcn_mfma_f32_32x32x16_bf16(k0, qf[ks], s0, 0, 0, 0);
          s1 = __builtin_amdgcn_mfma_f32_32x32x16_bf16(k1, qf[ks], s1, 0, 0, 0);
        }
        __builtin_amdgcn_s_setprio(0);

        if (!vmall) {   // rare general-mask path
#pragma unroll
          for (int r = 0; r < 16; ++r) {
            const int wk = (r & 3) + 8 * (r >> 2) + 4 * hi;
            s0[r] += (vmb[j0 + wk] - 1.0f) * 1.0e12f;
            s1[r] += (vmb[j0 + 32 + wk] - 1.0f) * 1.0e12f;
          }
        }
        if (j0 + 63 > qb + w * 32) {   // diagonal region only (wave-uniform)
#pragma unroll
          for (int r = 0; r < 16; ++r) {
            const int wk = (r & 3) + 8 * (r >> 2) + 4 * hi;
            if (j0 + wk > qrow) s0[r] = -1.0e12f;
            if (j0 + 32 + wk > qrow) s1[r] = -1.0e12f;
          }
        }

        // ---- row max: 31-op tree + 1 half-swap
        float m8[8];
#pragma unroll
        for (int r = 0; r < 8; ++r)
          m8[r] = fmaxf(fmaxf(s0[r], s0[r + 8]), fmaxf(s1[r], s1[r + 8]));
        float m4a = fmaxf(m8[0], m8[4]), m4b = fmaxf(m8[1], m8[5]);
        float m4c = fmaxf(m8[2], m8[6]), m4d = fmaxf(m8[3], m8[7]);
        const float mloc = fmaxf(fmaxf(m4a, m4b), fmaxf(m4c, m4d));
        const float mt = fmaxf(mloc, __shfl_xor(mloc, 32));

        // ---- defer-max rescale (wave-uniform trigger)
        if (!__all(mt <= m_i + 8.0f)) {
          const float mn = fmaxf(m_i, mt);
          const float al = EX2(m_i - mn);
          l_i *= al;
#pragma unroll
          for (int r = 0; r < 16; ++r) {
            const int qi = (r & 3) + 8 * (r >> 2) + 4 * hi;
            const float a2 = __shfl(al, qi);
            acc0[r] *= a2;
            acc1[r] *= a2;
          }
          m_i = mn;
        }

        // ---- p = 2^(s - m_i), row sum
        float sl2 = 0.f;
#pragma unroll
        for (int r = 0; r < 16; ++r) { s0[r] = EX2(s0[r] - m_i); sl2 += s0[r]; }
#pragma unroll
        for (int r = 0; r < 16; ++r) { s1[r] = EX2(s1[r] - m_i); sl2 += s1[r]; }
        l_i += sl2 + __shfl_xor(sl2, 32);

        // ---- in-register P -> PV A-fragments (16 pack + 16 swap + selects)
        unsigned W0[2][4], W1[2][4], X0[2][4], X1[2][4];
#pragma unroll
        for (int a = 0; a < 2; ++a)
#pragma unroll
          for (int m = 0; m < 4; ++m) {
            W0[a][m] = pk2bf(s0[8 * a + 2 * m], s0[8 * a + 2 * m + 1]);
            W1[a][m] = pk2bf(s1[8 * a + 2 * m], s1[8 * a + 2 * m + 1]);
          }
#pragma unroll
        for (int a = 0; a < 2; ++a)
#pragma unroll
          for (int m = 0; m < 4; ++m) {
            X0[a][m] = __shfl_xor((int)W0[a][m], 32);
            X1[a][m] = __shfl_xor((int)W1[a][m], 32);
          }

        __builtin_amdgcn_s_setprio(1);
#pragma unroll
        for (int ks = 0; ks < 4; ++ks) {
          const int a = ks & 1;
          union { bf16x8 v; unsigned u[4]; } pf;
          if (ks < 2) {
            pf.u[0] = hi ? X0[a][2] : W0[a][0];
            pf.u[1] = hi ? X0[a][3] : W0[a][1];
            pf.u[2] = hi ? W0[a][2] : X0[a][0];
            pf.u[3] = hi ? W0[a][3] : X0[a][1];
          } else {
            pf.u[0] = hi ? X1[a][2] : W1[a][0];
            pf.u[1] = hi ? X1[a][3] : W1[a][1];
            pf.u[2] = hi ? W1[a][2] : X1[a][0];
            pf.u[3] = hi ? W1[a][3] : X1[a][1];
          }
          const int sl = ((2 * ks + hi) ^ swz) * 8;
          const bf16x8 v0 = *(const bf16x8*)&Vtc[q5][sl];
          const bf16x8 v1 = *(const bf16x8*)&Vtc[32 + q5][sl];
          acc0 = __builtin_amdgcn_mfma_f32_32x32x16_bf16(pf.v, v0, acc0, 0, 0, 0);
          acc1 = __builtin_amdgcn_mfma_f32_32x32x16_bf16(pf.v, v1, acc1, 0, 0, 0);
        }
        __builtin_amdgcn_s_setprio(0);
      }

      asm volatile("s_waitcnt lgkmcnt(0)" ::: "memory");
      __builtin_amdgcn_s_barrier();
      cur ^= 1;
    }

    // ---- epilogue: normalize, transpose via padded LDS, coalesced store
    short (*tr)[72] = (short(*)[72])(smem + w * 4608);
    const float inv = 1.0f / l_i;
#pragma unroll
    for (int r = 0; r < 16; ++r) {
      const int qi = (r & 3) + 8 * (r >> 2) + 4 * hi;
      const float iv = __shfl(inv, qi);
      tr[qi][q5] = f2bf(acc0[r] * iv);
      tr[qi][32 + q5] = f2bf(acc1[r] * iv);
    }
    asm volatile("s_waitcnt lgkmcnt(0)" ::: "memory");
    const int rr = lane >> 1;
    const int cb = (lane & 1) * 32;
    short* dst =
        Ow + ((size_t)(b * S_LEN + qb + w * 32 + rr)) * DMODEL + h * DKEY + cb;
#pragma unroll
    for (int i = 0; i < 4; ++i) {
      const bf16x8 o = *(const bf16x8*)&tr[rr][cb + i * 8];
      *(bf16x8*)&dst[i * 8] = o;
    }
  }
}

// ---------------------------------------------------------------------------
// Kernel 3: output projection. 1 block/CU -> 4-deep ring hides HBM latency.
// ---------------------------------------------------------------------------
__global__ __launch_bounds__(256) void gemm_out(
    const short* __restrict__ A, const short* __restrict__ Wz,
    const float* __restrict__ bias, float* __restrict__ out) {
  __shared__ char smem[65536];   // 4 ring buffers x (A 8KB + B 8KB)

  const int m0 = blockIdx.x * 128, n0 = blockIdx.y * 128;
  const int t = threadIdx.x;
  const int lane = t & 63;
  const int w = t >> 6;
  const int quad = lane >> 4;
  const int l15 = lane & 15;
  const int wr = (w >> 1) * 64, wc = (w & 1) * 64;
  const int rswz = (quad ^ ((l15 >> 1) & 3)) * 8;

  const short* Abase = A + (size_t)m0 * DMODEL;
  const short* Bbase = Wz + (size_t)n0 * DMODEL;

  f32x4 acc[4][4] = {};

#pragma unroll
  for (int p = 0; p < 3; ++p) {
    stage_tile32(Abase + p * 32, (short(*)[32])(smem + p * 16384), w, lane);
    stage_tile32(Bbase + p * 32, (short(*)[32])(smem + p * 16384 + 8192), w, lane);
  }

  unsigned o0 = 0, o1 = 16384, o2 = 32768, o3 = 49152;
  for (int it = 0; it < 32; ++it) {
    if (it < 29) {
      const int kt = (it + 3) * 32;
      stage_tile32(Abase + kt, (short(*)[32])(smem + o3), w, lane);
      stage_tile32(Bbase + kt, (short(*)[32])(smem + o3 + 8192), w, lane);
    }
    if (it < 29)       asm volatile("s_waitcnt vmcnt(12)" ::: "memory");
    else if (it == 29) asm volatile("s_waitcnt vmcnt(8)" ::: "memory");
    else if (it == 30) asm volatile("s_waitcnt vmcnt(4)" ::: "memory");
    else               asm volatile("s_waitcnt vmcnt(0)" ::: "memory");
    __builtin_amdgcn_s_barrier();
    short (*As)[32] = (short(*)[32])(smem + o0);
    short (*Bs)[32] = (short(*)[32])(smem + o0 + 8192);
    bf16x8 bf[4], af[4];
#pragma unroll
    for (int nj = 0; nj < 4; ++nj)
      bf[nj] = *(const bf16x8*)&Bs[wc + nj * 16 + l15][rswz];
#pragma unroll
    for (int mi = 0; mi < 4; ++mi)
      af[mi] = *(const bf16x8*)&As[wr + mi * 16 + l15][rswz];
#pragma unroll
    for (int mi = 0; mi < 4; ++mi)
#pragma unroll
      for (int nj = 0; nj < 4; ++nj)
        acc[mi][nj] =
            __builtin_amdgcn_mfma_f32_16x16x32_bf16(af[mi], bf[nj], acc[mi][nj], 0, 0, 0);
    asm volatile("s_waitcnt lgkmcnt(0)" ::: "memory");
    __builtin_amdgcn_s_barrier();
    const unsigned tmp = o0; o0 = o1; o1 = o2; o2 = o3; o3 = tmp;
  }
#pragma unroll
  for (int nj = 0; nj < 4; ++nj) {
    const int n = n0 + wc + nj * 16 + l15;
    const float bval = bias[n];
#pragma unroll
    for (int ti = 0; ti < 4; ++ti)
#pragma unroll
      for (int r = 0; r < 4; ++r) {
        const int m = m0 + wr + ti * 16 + quad * 4 + r;
        out[(size_t)m * DMODEL + n] = acc[ti][nj][r] + bval;
      }
  }
}

// ---------------------------------------------------------------------------
extern "C" void kernel_launch(void* const* d_in, const int* in_sizes, int n_in,
                              void* d_out, int out_size, void* d_ws,
                              size_t ws_size, hipStream_t stream) {
  const float* q      = (const float*)d_in[0];
  const float* k      = (const float*)d_in[1];
  const float* v      = (const float*)d_in[2];
  const float* rope   = (const float*)d_in[3];
  const float* v_mask = (const float*)d_in[5];
  const float* Wq = (const float*)d_in[6];
  const float* bq = (const float*)d_in[7];
  const float* Wk = (const float*)d_in[8];
  const float* bk = (const float*)d_in[9];
  const float* Wv = (const float*)d_in[10];
  const float* bv = (const float*)d_in[11];
  const float* Wo = (const float*)d_in[12];
  const float* bo = (const float*)d_in[13];
  float* out = (float*)d_out;

  short* ws = (short*)d_ws;
  short* Qw = ws;                  // [bh][s][dk] bf16, 8 MB
  short* Kw = ws + 4194304;        // [bh][s][dk] bf16, 8 MB
  short* Vw = ws + 8388608;        // [bh][dk][s] bf16, 8 MB
  short* Ow = ws + 12582912;       // [b][s][dmodel] bf16, 8 MB
  short* Wt = ws + 16777216;       // 4x [n][k] bf16, 8 MB
  short* Xb = ws + 20971520;       // 3x [m][k] bf16, 24 MB  (total 64 MB)

  convert_x<<<dim3(4096, 3), 256, 0, stream>>>(q, k, v, Xb);
  convert_w<<<dim3(16, 16, 4), 256, 0, stream>>>(Wq, Wk, Wv, Wo, Wt);
  gemm_qkv<<<dim3(32, 8, 3), 256, 0, stream>>>(Xb, Wt, bq, bk, bv, rope,
                                               Qw, Kw, Vw);
  attn_kernel<<<dim3(16, 32), 256, 0, stream>>>(Qw, Kw, Vw, v_mask, Ow);
  gemm_out<<<dim3(32, 8), 256, 0, stream>>>(Ow, Wt + 3145728, bo, out);
}

// Round 5
// 259.341 us; speedup vs baseline: 1.0598x; 1.0598x over previous
//
#include <hip/hip_runtime.h>
#include <hip/hip_bf16.h>

#define S_LEN 2048
#define DMODEL 1024
#define NHEAD 16
#define DKEY 64

typedef __attribute__((ext_vector_type(8))) short bf16x8;
typedef __attribute__((ext_vector_type(4))) float f32x4;
typedef __attribute__((ext_vector_type(16))) float f32x16;

__device__ __forceinline__ short f2bf(float f) {
  union { float f; unsigned u; } a; a.f = f;
  unsigned u = a.u;
  u += 0x7fff + ((u >> 16) & 1);   // RTNE
  return (short)(u >> 16);
}
__device__ __forceinline__ unsigned pk2bf(float a, float b) {
  union { __hip_bfloat162 h; unsigned u; } c;
  c.h = __float22bfloat162_rn(float2{a, b});
  return c.u;
}
__device__ __forceinline__ void gl_lds16(const void* g, void* l) {
  __builtin_amdgcn_global_load_lds(
      (const __attribute__((address_space(1))) unsigned int*)g,
      (__attribute__((address_space(3))) unsigned int*)l, 16, 0, 0);
}
#define EX2(x) __builtin_amdgcn_exp2f(x)

// ---------------------------------------------------------------------------
// Kernel -1: X (q,k,v) fp32 -> bf16, elementwise. grid (4096, 3) x 256.
// ---------------------------------------------------------------------------
__global__ __launch_bounds__(256) void convert_x(
    const float* __restrict__ q, const float* __restrict__ k,
    const float* __restrict__ v, short* __restrict__ Xb) {
  const int z = blockIdx.y;
  const float* X = (z == 0) ? q : (z == 1) ? k : v;
  short* dst = Xb + (size_t)z * 4194304;
  const int i = (blockIdx.x * 256 + threadIdx.x) * 4;
  const float4 xv = *(const float4*)&X[i];
  uint2 o;
  o.x = pk2bf(xv.x, xv.y);
  o.y = pk2bf(xv.z, xv.w);
  *(uint2*)&dst[i] = o;
}

// ---------------------------------------------------------------------------
// Kernel 0: weight transpose+convert. W[k][n] f32 -> Wt[n][k] bf16, 4 weights.
// ---------------------------------------------------------------------------
__global__ __launch_bounds__(256) void convert_w(
    const float* __restrict__ Wq, const float* __restrict__ Wk,
    const float* __restrict__ Wv, const float* __restrict__ Wo,
    short* __restrict__ Wt) {
  __shared__ short T[64][72];
  const int z = blockIdx.z;
  const float* W = (z == 0) ? Wq : (z == 1) ? Wk : (z == 2) ? Wv : Wo;
  short* dst = Wt + (size_t)z * 1048576;
  const int k0 = blockIdx.x * 64, n0 = blockIdx.y * 64;
  const int t = threadIdx.x;
#pragma unroll
  for (int p = 0; p < 4; ++p) {
    const int r = p * 16 + (t >> 4), c = (t & 15) * 4;
    const float4 wv = *(const float4*)&W[(size_t)(k0 + r) * DMODEL + n0 + c];
    T[c + 0][r] = f2bf(wv.x);
    T[c + 1][r] = f2bf(wv.y);
    T[c + 2][r] = f2bf(wv.z);
    T[c + 3][r] = f2bf(wv.w);
  }
  __syncthreads();
  const int rr = t >> 2, cc = (t & 3) * 16;
  const bf16x8 x0 = *(const bf16x8*)&T[rr][cc];
  const bf16x8 x1 = *(const bf16x8*)&T[rr][cc + 8];
  short* d = dst + (size_t)(n0 + rr) * DMODEL + k0 + cc;
  *(bf16x8*)&d[0] = x0;
  *(bf16x8*)&d[8] = x1;
}

// ---------------------------------------------------------------------------
// Bf16 tile staging with bank-conflict-free XOR chunk swizzle.
// Each thread issues exactly 2 global_load_lds (vmcnt += 2 per call).
// ---------------------------------------------------------------------------
__device__ __forceinline__ void stage_tile32(const short* gbase, short (*tile)[32],
                                             int w, int lane) {
  const int row = lane >> 2;                          // 0..15 per issue
  const int g = ((lane & 3) ^ ((row >> 1) & 3)) * 8;  // swizzled global chunk
#pragma unroll
  for (int i = 0; i < 2; ++i) {
    const int r = w * 32 + i * 16 + row;
    gl_lds16(gbase + (size_t)r * DMODEL + g, &tile[w * 32 + i * 16][0]);
  }
}

// ---------------------------------------------------------------------------
// Kernel 1: QKV projection, 128x128 tile, BK=32, all-bf16, swizzled LDS.
// 3-deep ring pipeline with counted vmcnt. Q/K epilogue: f32 LDS transpose
// (2 half-passes), vectorized rope loads, coalesced 16B stores.
// z=0 Q (RoPE + exp2-domain scale -> [bh][s][dk]), z=1 K (RoPE), z=2 V^T.
// ---------------------------------------------------------------------------
__global__ __launch_bounds__(256) void gemm_qkv(
    const short* __restrict__ Xb, const short* __restrict__ Wt,
    const float* __restrict__ bq, const float* __restrict__ bk,
    const float* __restrict__ bv, const float* __restrict__ rope,
    short* __restrict__ Qw, short* __restrict__ Kw, short* __restrict__ Vw) {
  __shared__ char smem[49152];   // 3 ring buffers x (A 8KB + B 8KB)

  const int z = blockIdx.z;
  const short* X = Xb + (size_t)z * 4194304;
  const float* bias = (z == 0) ? bq : (z == 1) ? bk : bv;
  const short* Wz = Wt + (size_t)z * 1048576;

  const int m0 = blockIdx.x * 128, n0 = blockIdx.y * 128;
  const int t = threadIdx.x;
  const int lane = t & 63;
  const int w = t >> 6;
  const int quad = lane >> 4;
  const int l15 = lane & 15;
  const int wr = (w >> 1) * 64, wc = (w & 1) * 64;
  const int rswz = (quad ^ ((l15 >> 1) & 3)) * 8;  // frag-read swizzled offset

  const short* Abase = X + (size_t)m0 * DMODEL;
  const short* Bbase = Wz + (size_t)n0 * DMODEL;

  f32x4 acc[4][4] = {};

  // prologue: tiles 0 and 1 into ring slots 0,1
  stage_tile32(Abase + 0, (short(*)[32])(smem + 0), w, lane);
  stage_tile32(Bbase + 0, (short(*)[32])(smem + 8192), w, lane);
  stage_tile32(Abase + 32, (short(*)[32])(smem + 16384), w, lane);
  stage_tile32(Bbase + 32, (short(*)[32])(smem + 16384 + 8192), w, lane);

  unsigned oc = 0, on = 16384, of = 32768;   // cur / next / future offsets
  for (int it = 0; it < 32; ++it) {
    if (it < 30) {
      const int kt = (it + 2) * 32;
      stage_tile32(Abase + kt, (short(*)[32])(smem + of), w, lane);
      stage_tile32(Bbase + kt, (short(*)[32])(smem + of + 8192), w, lane);
    }
    if (it < 30)       asm volatile("s_waitcnt vmcnt(8)" ::: "memory");
    else if (it == 30) asm volatile("s_waitcnt vmcnt(4)" ::: "memory");
    else               asm volatile("s_waitcnt vmcnt(0)" ::: "memory");
    __builtin_amdgcn_s_barrier();
    short (*As)[32] = (short(*)[32])(smem + oc);
    short (*Bs)[32] = (short(*)[32])(smem + oc + 8192);
    bf16x8 bf[4], af[4];
#pragma unroll
    for (int nj = 0; nj < 4; ++nj)
      bf[nj] = *(const bf16x8*)&Bs[wc + nj * 16 + l15][rswz];
#pragma unroll
    for (int mi = 0; mi < 4; ++mi)
      af[mi] = *(const bf16x8*)&As[wr + mi * 16 + l15][rswz];
#pragma unroll
    for (int mi = 0; mi < 4; ++mi)
#pragma unroll
      for (int nj = 0; nj < 4; ++nj)
        acc[mi][nj] =
            __builtin_amdgcn_mfma_f32_16x16x32_bf16(af[mi], bf[nj], acc[mi][nj], 0, 0, 0);
    asm volatile("s_waitcnt lgkmcnt(0)" ::: "memory");
    __builtin_amdgcn_s_barrier();
    const unsigned tmp = oc; oc = on; on = of; of = tmp;
  }

  const int b = (m0 + wr) >> 11;
  const int sbase = (m0 + wr) & 2047;

  if (z == 2) {
    __syncthreads();
    short (*tr)[72] = (short(*)[72])(smem + w * 9216);
    const int h2 = (n0 + wc) >> 6;
#pragma unroll
    for (int nj = 0; nj < 4; ++nj) {
      const float bval = bias[n0 + wc + nj * 16 + l15];
#pragma unroll
      for (int ti = 0; ti < 4; ++ti)
#pragma unroll
        for (int r = 0; r < 4; ++r)
          tr[nj * 16 + l15][ti * 16 + quad * 4 + r] = f2bf(acc[ti][nj][r] + bval);
    }
    asm volatile("s_waitcnt lgkmcnt(0)" ::: "memory");
    const int bh2 = b * NHEAD + h2;
#pragma unroll
    for (int cc = 0; cc < 4; ++cc) {
      const int row = cc * 16 + (lane >> 2);
      const int c0 = (lane & 3) * 16;
      const bf16x8 x0 = *(const bf16x8*)&tr[row][c0];
      const bf16x8 x1 = *(const bf16x8*)&tr[row][c0 + 8];
      short* d = Vw + ((size_t)bh2 * DKEY + row) * S_LEN + sbase + c0;
      *(bf16x8*)&d[0] = x0;
      *(bf16x8*)&d[8] = x1;
    }
    return;
  }

  // ---- Q/K epilogue: f32 LDS transpose + vectorized rope + coalesced store
  short* outw = (z == 0) ? Qw : Kw;
  const float qs = (z == 0) ? 0.18033688011112042f : 1.0f;  // log2(e)/8 for Q
  const int h = (n0 + wc) >> 6;
  const int bh = b * NHEAD + h;
  float (*tqf)[33] = (float(*)[33])(smem + w * 8448);   // per-wave, 8448 B
#pragma unroll
  for (int half = 0; half < 2; ++half) {
    asm volatile("s_waitcnt lgkmcnt(0)" ::: "memory");   // WAR vs prev reads
#pragma unroll
    for (int nj2 = 0; nj2 < 2; ++nj2) {
      const int nj = half * 2 + nj2;
      const float bval = bias[n0 + wc + nj * 16 + l15];
#pragma unroll
      for (int ti = 0; ti < 4; ++ti)
#pragma unroll
        for (int r = 0; r < 4; ++r)
          tqf[ti * 16 + quad * 4 + r][nj2 * 16 + l15] =
              (acc[ti][nj][r] + bval) * qs;
    }
    asm volatile("s_waitcnt lgkmcnt(0)" ::: "memory");
    const int row = lane;                    // one s-row per lane
    float v[32];
#pragma unroll
    for (int i = 0; i < 8; ++i) {
      const float4 x = *(const float4*)&tqf[row][i * 4];
      v[i * 4 + 0] = x.x; v[i * 4 + 1] = x.y;
      v[i * 4 + 2] = x.z; v[i * 4 + 3] = x.w;
    }
    const int s = sbase + row;
    const float* rp = &rope[((size_t)b * S_LEN + s) * DKEY + half * 32];
    short* d = outw + ((size_t)bh * S_LEN + s) * DKEY + half * 32;
#pragma unroll
    for (int i = 0; i < 4; ++i) {            // 8 dk per i
      const float4 ra = *(const float4*)&rp[i * 8];
      const float4 rb = *(const float4*)&rp[i * 8 + 4];
      uint4 o;
      o.x = pk2bf(v[i*8+0]*ra.y - v[i*8+1]*ra.x, v[i*8+1]*ra.y + v[i*8+0]*ra.x);
      o.y = pk2bf(v[i*8+2]*ra.w - v[i*8+3]*ra.z, v[i*8+3]*ra.w + v[i*8+2]*ra.z);
      o.z = pk2bf(v[i*8+4]*rb.y - v[i*8+5]*rb.x, v[i*8+5]*rb.y + v[i*8+4]*rb.x);
      o.w = pk2bf(v[i*8+6]*rb.w - v[i*8+7]*rb.z, v[i*8+7]*rb.w + v[i*8+6]*rb.z);
      *(uint4*)&d[i * 8] = o;
    }
  }
}

// ---------------------------------------------------------------------------
// Kernel 2: causal flash attention, 32x32 MFMA + in-register softmax.
// ONE 128-row q-chunk per block (grid 16x32; R4's 2-pass version computed
// every chunk twice). 4 warps x 32 q-rows; KVBLK=64 double-buffered with
// counted vmcnt. Swapped QK^T (A=K, B=Q) puts a full q-row in each lane ->
// softmax = tree-max + 1 shfl_xor(32); P rebuilt in-register as PV A-operand
// -- no LDS round-trip. Pairing (c, 15-c) keeps co-resident blocks uniform.
// ---------------------------------------------------------------------------
__global__ __launch_bounds__(256, 2) void attn_kernel(
    const short* __restrict__ Qw, const short* __restrict__ Kw,
    const short* __restrict__ Vw, const float* __restrict__ v_mask,
    short* __restrict__ Ow) {
  __shared__ char smem[32768];   // Kt[2][64][64] 16KB + Vt[2][64][64] 16KB

  const int t = threadIdx.x;
  const int w = t >> 6;          // 0..3
  const int lane = t & 63;
  const int q5 = lane & 31;      // q-row within warp tile / d-lane for PV
  const int hi = lane >> 5;
  const int bh = blockIdx.y;
  const int b = bh >> 4;
  const int h = bh & 15;

  const short* Kbase = Kw + (size_t)bh * S_LEN * DKEY;
  const short* Vbase = Vw + (size_t)bh * DKEY * S_LEN;
  const float* vmb = v_mask + (size_t)b * S_LEN;

  const int sr0 = t >> 3;        // staging: 0..31 row per issue
  const int sch = t & 7;         // staging: chunk slot

  // strict all-ones v_mask check (fast path)
  int okm = 1;
  {
    const float4* vm4 = (const float4*)vmb;
#pragma unroll
    for (int i = 0; i < 8; ++i) {
      const float4 a = vm4[lane * 8 + i];
      okm &= (a.x == 1.0f) & (a.y == 1.0f) & (a.z == 1.0f) & (a.w == 1.0f);
    }
  }
  const bool vmall = __all(okm);

  int c = blockIdx.x;                       // 0..15 (128-row q-chunk)
  if (blockIdx.y & 16) c = 15 - c;          // co-resident balance (d, d+256)
  const int qb = c * 128;
  const int qrow = qb + w * 32 + q5;

  const short* Qp = Qw + ((size_t)bh * S_LEN + qrow) * DKEY;
  bf16x8 qf[4];
#pragma unroll
  for (int ks = 0; ks < 4; ++ks)
    qf[ks] = *(const bf16x8*)(Qp + ks * 16 + hi * 8);

  float m_i = -1.0e30f, l_i = 0.f;
  f32x16 acc0 = {}, acc1 = {};

  const int niter = 2 * c + 2;
  const int wlast = (qb + w * 32 + 31) >> 6;

  // prologue: stage tile 0 into buf 0 (4 gl_lds per thread)
#pragma unroll
  for (int i = 0; i < 2; ++i) {
    const int row = i * 32 + sr0;
    const int g = sch ^ (row & 7);
    gl_lds16(Kbase + (size_t)row * DKEY + g * 8,
             smem + row * 128 + sch * 16);
    gl_lds16(Vbase + (size_t)row * S_LEN + g * 8,
             smem + 16384 + row * 128 + sch * 16);
  }

  int cur = 0;
  for (int it = 0; it < niter; ++it) {
    const int j0 = it * 64;
    if (it + 1 < niter) {   // prefetch next tile into buf^1
      const int jn = j0 + 64;
      char* kb = smem + (cur ^ 1) * 8192;
      char* vb = smem + 16384 + (cur ^ 1) * 8192;
#pragma unroll
      for (int i = 0; i < 2; ++i) {
        const int row = i * 32 + sr0;
        const int g = sch ^ (row & 7);
        gl_lds16(Kbase + (size_t)(jn + row) * DKEY + g * 8,
                 kb + row * 128 + sch * 16);
        gl_lds16(Vbase + (size_t)row * S_LEN + jn + g * 8,
                 vb + row * 128 + sch * 16);
      }
      asm volatile("s_waitcnt vmcnt(4)" ::: "memory");
    } else {
      asm volatile("s_waitcnt vmcnt(0)" ::: "memory");
    }
    __builtin_amdgcn_s_barrier();

    if (it <= wlast) {
      short (*Ktc)[64] = (short(*)[64])(smem + cur * 8192);
      short (*Vtc)[64] = (short(*)[64])(smem + 16384 + cur * 8192);
      const int swz = q5 & 7;

      // ---- QK^T: S[key][q], two 32-key halves
      f32x16 s0 = {}, s1 = {};
      __builtin_amdgcn_s_setprio(1);
#pragma unroll
      for (int ks = 0; ks < 4; ++ks) {
        const int sl = ((2 * ks + hi) ^ swz) * 8;
        const bf16x8 k0 = *(const bf16x8*)&Ktc[q5][sl];
        const bf16x8 k1 = *(const bf16x8*)&Ktc[32 + q5][sl];
        s0 = __builtin_amdgcn_mfma_f32_32x32x16_bf16(k0, qf[ks], s0, 0, 0, 0);
        s1 = __builtin_amdgcn_mfma_f32_32x32x16_bf16(k1, qf[ks], s1, 0, 0, 0);
      }
      __builtin_amdgcn_s_setprio(0);

      if (!vmall) {   // rare general-mask path
#pragma unroll
        for (int r = 0; r < 16; ++r) {
          const int wk = (r & 3) + 8 * (r >> 2) + 4 * hi;
          s0[r] += (vmb[j0 + wk] - 1.0f) * 1.0e12f;
          s1[r] += (vmb[j0 + 32 + wk] - 1.0f) * 1.0e12f;
        }
      }
      if (j0 + 63 > qb + w * 32) {   // diagonal region only (wave-uniform)
#pragma unroll
        for (int r = 0; r < 16; ++r) {
          const int wk = (r & 3) + 8 * (r >> 2) + 4 * hi;
          if (j0 + wk > qrow) s0[r] = -1.0e12f;
          if (j0 + 32 + wk > qrow) s1[r] = -1.0e12f;
        }
      }

      // ---- row max: tree + 1 half-swap
      float m8[8];
#pragma unroll
      for (int r = 0; r < 8; ++r)
        m8[r] = fmaxf(fmaxf(s0[r], s0[r + 8]), fmaxf(s1[r], s1[r + 8]));
      float m4a = fmaxf(m8[0], m8[4]), m4b = fmaxf(m8[1], m8[5]);
      float m4c = fmaxf(m8[2], m8[6]), m4d = fmaxf(m8[3], m8[7]);
      const float mloc = fmaxf(fmaxf(m4a, m4b), fmaxf(m4c, m4d));
      const float mt = fmaxf(mloc, __shfl_xor(mloc, 32));

      // ---- defer-max rescale (wave-uniform trigger)
      if (!__all(mt <= m_i + 8.0f)) {
        const float mn = fmaxf(m_i, mt);
        const float al = EX2(m_i - mn);
        l_i *= al;
#pragma unroll
        for (int r = 0; r < 16; ++r) {
          const int qi = (r & 3) + 8 * (r >> 2) + 4 * hi;
          const float a2 = __shfl(al, qi);
          acc0[r] *= a2;
          acc1[r] *= a2;
        }
        m_i = mn;
      }

      // ---- p = 2^(s - m_i), row sum
      float sl2 = 0.f;
#pragma unroll
      for (int r = 0; r < 16; ++r) { s0[r] = EX2(s0[r] - m_i); sl2 += s0[r]; }
#pragma unroll
      for (int r = 0; r < 16; ++r) { s1[r] = EX2(s1[r] - m_i); sl2 += s1[r]; }
      l_i += sl2 + __shfl_xor(sl2, 32);

      // ---- in-register P -> PV A-fragments (16 pack + 16 swap + selects)
      unsigned W0[2][4], W1[2][4], X0[2][4], X1[2][4];
#pragma unroll
      for (int a = 0; a < 2; ++a)
#pragma unroll
        for (int m = 0; m < 4; ++m) {
          W0[a][m] = pk2bf(s0[8 * a + 2 * m], s0[8 * a + 2 * m + 1]);
          W1[a][m] = pk2bf(s1[8 * a + 2 * m], s1[8 * a + 2 * m + 1]);
        }
#pragma unroll
      for (int a = 0; a < 2; ++a)
#pragma unroll
        for (int m = 0; m < 4; ++m) {
          X0[a][m] = __shfl_xor((int)W0[a][m], 32);
          X1[a][m] = __shfl_xor((int)W1[a][m], 32);
        }

      __builtin_amdgcn_s_setprio(1);
#pragma unroll
      for (int ks = 0; ks < 4; ++ks) {
        const int a = ks & 1;
        union { bf16x8 v; unsigned u[4]; } pf;
        if (ks < 2) {
          pf.u[0] = hi ? X0[a][2] : W0[a][0];
          pf.u[1] = hi ? X0[a][3] : W0[a][1];
          pf.u[2] = hi ? W0[a][2] : X0[a][0];
          pf.u[3] = hi ? W0[a][3] : X0[a][1];
        } else {
          pf.u[0] = hi ? X1[a][2] : W1[a][0];
          pf.u[1] = hi ? X1[a][3] : W1[a][1];
          pf.u[2] = hi ? W1[a][2] : X1[a][0];
          pf.u[3] = hi ? W1[a][3] : X1[a][1];
        }
        const int sl = ((2 * ks + hi) ^ swz) * 8;
        const bf16x8 v0 = *(const bf16x8*)&Vtc[q5][sl];
        const bf16x8 v1 = *(const bf16x8*)&Vtc[32 + q5][sl];
        acc0 = __builtin_amdgcn_mfma_f32_32x32x16_bf16(pf.v, v0, acc0, 0, 0, 0);
        acc1 = __builtin_amdgcn_mfma_f32_32x32x16_bf16(pf.v, v1, acc1, 0, 0, 0);
      }
      __builtin_amdgcn_s_setprio(0);
    }

    asm volatile("s_waitcnt lgkmcnt(0)" ::: "memory");
    __builtin_amdgcn_s_barrier();
    cur ^= 1;
  }

  // ---- epilogue: normalize, transpose via padded LDS, coalesced store
  short (*tr)[72] = (short(*)[72])(smem + w * 4608);
  const float inv = 1.0f / l_i;
#pragma unroll
  for (int r = 0; r < 16; ++r) {
    const int qi = (r & 3) + 8 * (r >> 2) + 4 * hi;
    const float iv = __shfl(inv, qi);
    tr[qi][q5] = f2bf(acc0[r] * iv);
    tr[qi][32 + q5] = f2bf(acc1[r] * iv);
  }
  asm volatile("s_waitcnt lgkmcnt(0)" ::: "memory");
  const int rr = lane >> 1;
  const int cb = (lane & 1) * 32;
  short* dst =
      Ow + ((size_t)(b * S_LEN + qb + w * 32 + rr)) * DMODEL + h * DKEY + cb;
#pragma unroll
  for (int i = 0; i < 4; ++i) {
    const bf16x8 o = *(const bf16x8*)&tr[rr][cb + i * 8];
    *(bf16x8*)&dst[i * 8] = o;
  }
}

// ---------------------------------------------------------------------------
// Kernel 3: output projection. 1 block/CU -> 4-deep ring hides HBM latency.
// ---------------------------------------------------------------------------
__global__ __launch_bounds__(256) void gemm_out(
    const short* __restrict__ A, const short* __restrict__ Wz,
    const float* __restrict__ bias, float* __restrict__ out) {
  __shared__ char smem[65536];   // 4 ring buffers x (A 8KB + B 8KB)

  const int m0 = blockIdx.x * 128, n0 = blockIdx.y * 128;
  const int t = threadIdx.x;
  const int lane = t & 63;
  const int w = t >> 6;
  const int quad = lane >> 4;
  const int l15 = lane & 15;
  const int wr = (w >> 1) * 64, wc = (w & 1) * 64;
  const int rswz = (quad ^ ((l15 >> 1) & 3)) * 8;

  const short* Abase = A + (size_t)m0 * DMODEL;
  const short* Bbase = Wz + (size_t)n0 * DMODEL;

  f32x4 acc[4][4] = {};

#pragma unroll
  for (int p = 0; p < 3; ++p) {
    stage_tile32(Abase + p * 32, (short(*)[32])(smem + p * 16384), w, lane);
    stage_tile32(Bbase + p * 32, (short(*)[32])(smem + p * 16384 + 8192), w, lane);
  }

  unsigned o0 = 0, o1 = 16384, o2 = 32768, o3 = 49152;
  for (int it = 0; it < 32; ++it) {
    if (it < 29) {
      const int kt = (it + 3) * 32;
      stage_tile32(Abase + kt, (short(*)[32])(smem + o3), w, lane);
      stage_tile32(Bbase + kt, (short(*)[32])(smem + o3 + 8192), w, lane);
    }
    if (it < 29)       asm volatile("s_waitcnt vmcnt(12)" ::: "memory");
    else if (it == 29) asm volatile("s_waitcnt vmcnt(8)" ::: "memory");
    else if (it == 30) asm volatile("s_waitcnt vmcnt(4)" ::: "memory");
    else               asm volatile("s_waitcnt vmcnt(0)" ::: "memory");
    __builtin_amdgcn_s_barrier();
    short (*As)[32] = (short(*)[32])(smem + o0);
    short (*Bs)[32] = (short(*)[32])(smem + o0 + 8192);
    bf16x8 bf[4], af[4];
#pragma unroll
    for (int nj = 0; nj < 4; ++nj)
      bf[nj] = *(const bf16x8*)&Bs[wc + nj * 16 + l15][rswz];
#pragma unroll
    for (int mi = 0; mi < 4; ++mi)
      af[mi] = *(const bf16x8*)&As[wr + mi * 16 + l15][rswz];
#pragma unroll
    for (int mi = 0; mi < 4; ++mi)
#pragma unroll
      for (int nj = 0; nj < 4; ++nj)
        acc[mi][nj] =
            __builtin_amdgcn_mfma_f32_16x16x32_bf16(af[mi], bf[nj], acc[mi][nj], 0, 0, 0);
    asm volatile("s_waitcnt lgkmcnt(0)" ::: "memory");
    __builtin_amdgcn_s_barrier();
    const unsigned tmp = o0; o0 = o1; o1 = o2; o2 = o3; o3 = tmp;
  }
#pragma unroll
  for (int nj = 0; nj < 4; ++nj) {
    const int n = n0 + wc + nj * 16 + l15;
    const float bval = bias[n];
#pragma unroll
    for (int ti = 0; ti < 4; ++ti)
#pragma unroll
      for (int r = 0; r < 4; ++r) {
        const int m = m0 + wr + ti * 16 + quad * 4 + r;
        out[(size_t)m * DMODEL + n] = acc[ti][nj][r] + bval;
      }
  }
}

// ---------------------------------------------------------------------------
extern "C" void kernel_launch(void* const* d_in, const int* in_sizes, int n_in,
                              void* d_out, int out_size, void* d_ws,
                              size_t ws_size, hipStream_t stream) {
  const float* q      = (const float*)d_in[0];
  const float* k      = (const float*)d_in[1];
  const float* v      = (const float*)d_in[2];
  const float* rope   = (const float*)d_in[3];
  const float* v_mask = (const float*)d_in[5];
  const float* Wq = (const float*)d_in[6];
  const float* bq = (const float*)d_in[7];
  const float* Wk = (const float*)d_in[8];
  const float* bk = (const float*)d_in[9];
  const float* Wv = (const float*)d_in[10];
  const float* bv = (const float*)d_in[11];
  const float* Wo = (const float*)d_in[12];
  const float* bo = (const float*)d_in[13];
  float* out = (float*)d_out;

  short* ws = (short*)d_ws;
  short* Qw = ws;                  // [bh][s][dk] bf16, 8 MB
  short* Kw = ws + 4194304;        // [bh][s][dk] bf16, 8 MB
  short* Vw = ws + 8388608;        // [bh][dk][s] bf16, 8 MB
  short* Ow = ws + 12582912;       // [b][s][dmodel] bf16, 8 MB
  short* Wt = ws + 16777216;       // 4x [n][k] bf16, 8 MB
  short* Xb = ws + 20971520;       // 3x [m][k] bf16, 24 MB  (total 64 MB)

  convert_x<<<dim3(4096, 3), 256, 0, stream>>>(q, k, v, Xb);
  convert_w<<<dim3(16, 16, 4), 256, 0, stream>>>(Wq, Wk, Wv, Wo, Wt);
  gemm_qkv<<<dim3(32, 8, 3), 256, 0, stream>>>(Xb, Wt, bq, bk, bv, rope,
                                               Qw, Kw, Vw);
  attn_kernel<<<dim3(16, 32), 256, 0, stream>>>(Qw, Kw, Vw, v_mask, Ow);
  gemm_out<<<dim3(32, 8), 256, 0, stream>>>(Ow, Wt + 3145728, bo, out);
}

// Round 6
// 256.713 us; speedup vs baseline: 1.0706x; 1.0102x over previous
//
#include <hip/hip_runtime.h>
#include <hip/hip_bf16.h>

#define S_LEN 2048
#define DMODEL 1024
#define NHEAD 16
#define DKEY 64

typedef __attribute__((ext_vector_type(8))) short bf16x8;
typedef __attribute__((ext_vector_type(4))) float f32x4;
typedef __attribute__((ext_vector_type(16))) float f32x16;

__device__ __forceinline__ short f2bf(float f) {
  union { float f; unsigned u; } a; a.f = f;
  unsigned u = a.u;
  u += 0x7fff + ((u >> 16) & 1);   // RTNE
  return (short)(u >> 16);
}
__device__ __forceinline__ unsigned pk2bf(float a, float b) {
  union { __hip_bfloat162 h; unsigned u; } c;
  c.h = __float22bfloat162_rn(float2{a, b});
  return c.u;
}
__device__ __forceinline__ void gl_lds16(const void* g, void* l) {
  __builtin_amdgcn_global_load_lds(
      (const __attribute__((address_space(1))) unsigned int*)g,
      (__attribute__((address_space(3))) unsigned int*)l, 16, 0, 0);
}
#define EX2(x) __builtin_amdgcn_exp2f(x)

// ---------------------------------------------------------------------------
// Kernel -1: X (q,k,v) fp32 -> bf16, elementwise. grid (4096, 3) x 256.
// ---------------------------------------------------------------------------
__global__ __launch_bounds__(256) void convert_x(
    const float* __restrict__ q, const float* __restrict__ k,
    const float* __restrict__ v, short* __restrict__ Xb) {
  const int z = blockIdx.y;
  const float* X = (z == 0) ? q : (z == 1) ? k : v;
  short* dst = Xb + (size_t)z * 4194304;
  const int i = (blockIdx.x * 256 + threadIdx.x) * 4;
  const float4 xv = *(const float4*)&X[i];
  uint2 o;
  o.x = pk2bf(xv.x, xv.y);
  o.y = pk2bf(xv.z, xv.w);
  *(uint2*)&dst[i] = o;
}

// ---------------------------------------------------------------------------
// Kernel 0: weight transpose+convert. W[k][n] f32 -> Wt[n][k] bf16, 4 weights.
// ---------------------------------------------------------------------------
__global__ __launch_bounds__(256) void convert_w(
    const float* __restrict__ Wq, const float* __restrict__ Wk,
    const float* __restrict__ Wv, const float* __restrict__ Wo,
    short* __restrict__ Wt) {
  __shared__ short T[64][72];
  const int z = blockIdx.z;
  const float* W = (z == 0) ? Wq : (z == 1) ? Wk : (z == 2) ? Wv : Wo;
  short* dst = Wt + (size_t)z * 1048576;
  const int k0 = blockIdx.x * 64, n0 = blockIdx.y * 64;
  const int t = threadIdx.x;
#pragma unroll
  for (int p = 0; p < 4; ++p) {
    const int r = p * 16 + (t >> 4), c = (t & 15) * 4;
    const float4 wv = *(const float4*)&W[(size_t)(k0 + r) * DMODEL + n0 + c];
    T[c + 0][r] = f2bf(wv.x);
    T[c + 1][r] = f2bf(wv.y);
    T[c + 2][r] = f2bf(wv.z);
    T[c + 3][r] = f2bf(wv.w);
  }
  __syncthreads();
  const int rr = t >> 2, cc = (t & 3) * 16;
  const bf16x8 x0 = *(const bf16x8*)&T[rr][cc];
  const bf16x8 x1 = *(const bf16x8*)&T[rr][cc + 8];
  short* d = dst + (size_t)(n0 + rr) * DMODEL + k0 + cc;
  *(bf16x8*)&d[0] = x0;
  *(bf16x8*)&d[8] = x1;
}

// ---------------------------------------------------------------------------
// Bf16 tile staging with bank-conflict-free XOR chunk swizzle.
// Each thread issues exactly 2 global_load_lds (vmcnt += 2 per call).
// ---------------------------------------------------------------------------
__device__ __forceinline__ void stage_tile32(const short* gbase, short (*tile)[32],
                                             int w, int lane) {
  const int row = lane >> 2;                          // 0..15 per issue
  const int g = ((lane & 3) ^ ((row >> 1) & 3)) * 8;  // swizzled global chunk
#pragma unroll
  for (int i = 0; i < 2; ++i) {
    const int r = w * 32 + i * 16 + row;
    gl_lds16(gbase + (size_t)r * DMODEL + g, &tile[w * 32 + i * 16][0]);
  }
}

// ---------------------------------------------------------------------------
// Kernel 1: QKV projection, 128x128 tile, BK=32, all-bf16, swizzled LDS.
// 3-deep ring pipeline with counted vmcnt. Q/K epilogue: f32 LDS transpose
// (2 half-passes), vectorized rope loads, coalesced 16B stores.
// z=0 Q (RoPE + exp2-domain scale -> [bh][s][dk]), z=1 K (RoPE), z=2 V^T.
// ---------------------------------------------------------------------------
__global__ __launch_bounds__(256) void gemm_qkv(
    const short* __restrict__ Xb, const short* __restrict__ Wt,
    const float* __restrict__ bq, const float* __restrict__ bk,
    const float* __restrict__ bv, const float* __restrict__ rope,
    short* __restrict__ Qw, short* __restrict__ Kw, short* __restrict__ Vw) {
  __shared__ char smem[49152];   // 3 ring buffers x (A 8KB + B 8KB)

  const int z = blockIdx.z;
  const short* X = Xb + (size_t)z * 4194304;
  const float* bias = (z == 0) ? bq : (z == 1) ? bk : bv;
  const short* Wz = Wt + (size_t)z * 1048576;

  const int m0 = blockIdx.x * 128, n0 = blockIdx.y * 128;
  const int t = threadIdx.x;
  const int lane = t & 63;
  const int w = t >> 6;
  const int quad = lane >> 4;
  const int l15 = lane & 15;
  const int wr = (w >> 1) * 64, wc = (w & 1) * 64;
  const int rswz = (quad ^ ((l15 >> 1) & 3)) * 8;  // frag-read swizzled offset

  const short* Abase = X + (size_t)m0 * DMODEL;
  const short* Bbase = Wz + (size_t)n0 * DMODEL;

  f32x4 acc[4][4] = {};

  // prologue: tiles 0 and 1 into ring slots 0,1
  stage_tile32(Abase + 0, (short(*)[32])(smem + 0), w, lane);
  stage_tile32(Bbase + 0, (short(*)[32])(smem + 8192), w, lane);
  stage_tile32(Abase + 32, (short(*)[32])(smem + 16384), w, lane);
  stage_tile32(Bbase + 32, (short(*)[32])(smem + 16384 + 8192), w, lane);

  unsigned oc = 0, on = 16384, of = 32768;   // cur / next / future offsets
  for (int it = 0; it < 32; ++it) {
    if (it < 30) {
      const int kt = (it + 2) * 32;
      stage_tile32(Abase + kt, (short(*)[32])(smem + of), w, lane);
      stage_tile32(Bbase + kt, (short(*)[32])(smem + of + 8192), w, lane);
    }
    if (it < 30)       asm volatile("s_waitcnt vmcnt(8)" ::: "memory");
    else if (it == 30) asm volatile("s_waitcnt vmcnt(4)" ::: "memory");
    else               asm volatile("s_waitcnt vmcnt(0)" ::: "memory");
    __builtin_amdgcn_s_barrier();
    short (*As)[32] = (short(*)[32])(smem + oc);
    short (*Bs)[32] = (short(*)[32])(smem + oc + 8192);
    bf16x8 bf[4], af[4];
#pragma unroll
    for (int nj = 0; nj < 4; ++nj)
      bf[nj] = *(const bf16x8*)&Bs[wc + nj * 16 + l15][rswz];
#pragma unroll
    for (int mi = 0; mi < 4; ++mi)
      af[mi] = *(const bf16x8*)&As[wr + mi * 16 + l15][rswz];
#pragma unroll
    for (int mi = 0; mi < 4; ++mi)
#pragma unroll
      for (int nj = 0; nj < 4; ++nj)
        acc[mi][nj] =
            __builtin_amdgcn_mfma_f32_16x16x32_bf16(af[mi], bf[nj], acc[mi][nj], 0, 0, 0);
    asm volatile("s_waitcnt lgkmcnt(0)" ::: "memory");
    __builtin_amdgcn_s_barrier();
    const unsigned tmp = oc; oc = on; on = of; of = tmp;
  }

  const int b = (m0 + wr) >> 11;
  const int sbase = (m0 + wr) & 2047;

  if (z == 2) {
    __syncthreads();
    short (*tr)[72] = (short(*)[72])(smem + w * 9216);
    const int h2 = (n0 + wc) >> 6;
#pragma unroll
    for (int nj = 0; nj < 4; ++nj) {
      const float bval = bias[n0 + wc + nj * 16 + l15];
#pragma unroll
      for (int ti = 0; ti < 4; ++ti)
#pragma unroll
        for (int r = 0; r < 4; ++r)
          tr[nj * 16 + l15][ti * 16 + quad * 4 + r] = f2bf(acc[ti][nj][r] + bval);
    }
    asm volatile("s_waitcnt lgkmcnt(0)" ::: "memory");
    const int bh2 = b * NHEAD + h2;
#pragma unroll
    for (int cc = 0; cc < 4; ++cc) {
      const int row = cc * 16 + (lane >> 2);
      const int c0 = (lane & 3) * 16;
      const bf16x8 x0 = *(const bf16x8*)&tr[row][c0];
      const bf16x8 x1 = *(const bf16x8*)&tr[row][c0 + 8];
      short* d = Vw + ((size_t)bh2 * DKEY + row) * S_LEN + sbase + c0;
      *(bf16x8*)&d[0] = x0;
      *(bf16x8*)&d[8] = x1;
    }
    return;
  }

  // ---- Q/K epilogue: f32 LDS transpose + vectorized rope + coalesced store
  short* outw = (z == 0) ? Qw : Kw;
  const float qs = (z == 0) ? 0.18033688011112042f : 1.0f;  // log2(e)/8 for Q
  const int h = (n0 + wc) >> 6;
  const int bh = b * NHEAD + h;
  float (*tqf)[33] = (float(*)[33])(smem + w * 8448);   // per-wave, 8448 B
#pragma unroll
  for (int half = 0; half < 2; ++half) {
    asm volatile("s_waitcnt lgkmcnt(0)" ::: "memory");   // WAR vs prev reads
#pragma unroll
    for (int nj2 = 0; nj2 < 2; ++nj2) {
      const int nj = half * 2 + nj2;
      const float bval = bias[n0 + wc + nj * 16 + l15];
#pragma unroll
      for (int ti = 0; ti < 4; ++ti)
#pragma unroll
        for (int r = 0; r < 4; ++r)
          tqf[ti * 16 + quad * 4 + r][nj2 * 16 + l15] =
              (acc[ti][nj][r] + bval) * qs;
    }
    asm volatile("s_waitcnt lgkmcnt(0)" ::: "memory");
    const int row = lane;                    // one s-row per lane
    float v[32];
#pragma unroll
    for (int i = 0; i < 8; ++i) {
      const float4 x = *(const float4*)&tqf[row][i * 4];
      v[i * 4 + 0] = x.x; v[i * 4 + 1] = x.y;
      v[i * 4 + 2] = x.z; v[i * 4 + 3] = x.w;
    }
    const int s = sbase + row;
    const float* rp = &rope[((size_t)b * S_LEN + s) * DKEY + half * 32];
    short* d = outw + ((size_t)bh * S_LEN + s) * DKEY + half * 32;
#pragma unroll
    for (int i = 0; i < 4; ++i) {            // 8 dk per i
      const float4 ra = *(const float4*)&rp[i * 8];
      const float4 rb = *(const float4*)&rp[i * 8 + 4];
      uint4 o;
      o.x = pk2bf(v[i*8+0]*ra.y - v[i*8+1]*ra.x, v[i*8+1]*ra.y + v[i*8+0]*ra.x);
      o.y = pk2bf(v[i*8+2]*ra.w - v[i*8+3]*ra.z, v[i*8+3]*ra.w + v[i*8+2]*ra.z);
      o.z = pk2bf(v[i*8+4]*rb.y - v[i*8+5]*rb.x, v[i*8+5]*rb.y + v[i*8+4]*rb.x);
      o.w = pk2bf(v[i*8+6]*rb.w - v[i*8+7]*rb.z, v[i*8+7]*rb.w + v[i*8+6]*rb.z);
      *(uint4*)&d[i * 8] = o;
    }
  }
}

// ---------------------------------------------------------------------------
// Kernel 2: causal flash attention, 32x32 MFMA + in-register softmax +
// KEY-SPLIT: 512 thr = 8 warps; group A (w0-3) even key-tiles, group B (w4-7)
// odd key-tiles, same 128 q-rows. Doubles waves/CU (16) and halves each
// wave's serial tile count. K/V in a 4-slot LDS ring (64KB) with counted
// vmcnt. End: lane-aligned online-softmax merge (B writes acc/m/l f32 to
// LDS; A combines, normalizes, stores). Pairing (c,15-c) balances blocks.
// ---------------------------------------------------------------------------
__global__ __launch_bounds__(512, 4) void attn_kernel(
    const short* __restrict__ Qw, const short* __restrict__ Kw,
    const short* __restrict__ Vw, const float* __restrict__ v_mask,
    short* __restrict__ Ow) {
  __shared__ char smem[65536];   // K ring 4x8KB @0 | V ring 4x8KB @32768

  const int t = threadIdx.x;
  const int w = t >> 6;          // 0..7
  const int wq = w & 3;          // q-subtile (32 rows)
  const int grp = w >> 2;        // 0: even tiles, 1: odd tiles
  const int lane = t & 63;
  const int q5 = lane & 31;
  const int hi = lane >> 5;
  const int bh = blockIdx.y;
  const int b = bh >> 4;
  const int h = bh & 15;

  const short* Kbase = Kw + (size_t)bh * S_LEN * DKEY;
  const short* Vbase = Vw + (size_t)bh * DKEY * S_LEN;
  const float* vmb = v_mask + (size_t)b * S_LEN;

  const int sr = t >> 3;         // 0..63 staging row (512 thr, 1 ld/tile each)
  const int sch = t & 7;         // staging chunk slot

  // strict all-ones v_mask check (fast path)
  int okm = 1;
  {
    const float4* vm4 = (const float4*)vmb;
#pragma unroll
    for (int i = 0; i < 8; ++i) {
      const float4 a = vm4[lane * 8 + i];
      okm &= (a.x == 1.0f) & (a.y == 1.0f) & (a.z == 1.0f) & (a.w == 1.0f);
    }
  }
  const bool vmall = __all(okm);

  int c = blockIdx.x;                       // 0..15 (128-row q-chunk)
  if (blockIdx.y & 16) c = 15 - c;          // co-resident balance (d, d+256)
  const int qb = c * 128;
  const int qrow = qb + wq * 32 + q5;

  const short* Qp = Qw + ((size_t)bh * S_LEN + qrow) * DKEY;
  bf16x8 qf[4];
#pragma unroll
  for (int ks = 0; ks < 4; ++ks)
    qf[ks] = *(const bf16x8*)(Qp + ks * 16 + hi * 8);

  float m_i = -1.0e30f, l_i = 0.f;
  f32x16 acc0 = {}, acc1 = {};

  const int wlast = (qb + wq * 32 + 31) >> 6;   // last tile this warp needs
  const int gsw = sch ^ (sr & 7);               // staging swizzled chunk

  // prologue: stage tiles 0,1 into slots 0,1 (2 gl_lds per thread per tile)
#pragma unroll
  for (int p = 0; p < 2; ++p) {
    gl_lds16(Kbase + (size_t)(p * 64 + sr) * DKEY + gsw * 8,
             smem + p * 8192 + sr * 128 + sch * 16);
    gl_lds16(Vbase + (size_t)sr * S_LEN + p * 64 + gsw * 8,
             smem + 32768 + p * 8192 + sr * 128 + sch * 16);
  }

  for (int j = 0; j <= c; ++j) {
    if (j < c) {   // prefetch pair (2j+2, 2j+3) into slots (2j+2)&3,(2j+3)&3
#pragma unroll
      for (int p = 0; p < 2; ++p) {
        const int it2 = 2 * j + 2 + p;
        const int slot = it2 & 3;
        gl_lds16(Kbase + (size_t)(it2 * 64 + sr) * DKEY + gsw * 8,
                 smem + slot * 8192 + sr * 128 + sch * 16);
        gl_lds16(Vbase + (size_t)sr * S_LEN + it2 * 64 + gsw * 8,
                 smem + 32768 + slot * 8192 + sr * 128 + sch * 16);
      }
      asm volatile("s_waitcnt vmcnt(4)" ::: "memory");
    } else {
      asm volatile("s_waitcnt vmcnt(0)" ::: "memory");
    }
    __builtin_amdgcn_s_barrier();

    const int it = 2 * j + grp;
    if (it <= wlast) {
      const int slot = it & 3;
      const int j0 = it * 64;
      short (*Ktc)[64] = (short(*)[64])(smem + slot * 8192);
      short (*Vtc)[64] = (short(*)[64])(smem + 32768 + slot * 8192);
      const int swz = q5 & 7;

      // ---- QK^T: S[key][q], two 32-key halves
      f32x16 s0 = {}, s1 = {};
      __builtin_amdgcn_s_setprio(1);
#pragma unroll
      for (int ks = 0; ks < 4; ++ks) {
        const int sl = ((2 * ks + hi) ^ swz) * 8;
        const bf16x8 k0 = *(const bf16x8*)&Ktc[q5][sl];
        const bf16x8 k1 = *(const bf16x8*)&Ktc[32 + q5][sl];
        s0 = __builtin_amdgcn_mfma_f32_32x32x16_bf16(k0, qf[ks], s0, 0, 0, 0);
        s1 = __builtin_amdgcn_mfma_f32_32x32x16_bf16(k1, qf[ks], s1, 0, 0, 0);
      }
      __builtin_amdgcn_s_setprio(0);

      if (!vmall) {   // rare general-mask path
#pragma unroll
        for (int r = 0; r < 16; ++r) {
          const int wk = (r & 3) + 8 * (r >> 2) + 4 * hi;
          s0[r] += (vmb[j0 + wk] - 1.0f) * 1.0e12f;
          s1[r] += (vmb[j0 + 32 + wk] - 1.0f) * 1.0e12f;
        }
      }
      if (j0 + 63 > qb + wq * 32) {   // diagonal region only (wave-uniform)
#pragma unroll
        for (int r = 0; r < 16; ++r) {
          const int wk = (r & 3) + 8 * (r >> 2) + 4 * hi;
          if (j0 + wk > qrow) s0[r] = -1.0e12f;
          if (j0 + 32 + wk > qrow) s1[r] = -1.0e12f;
        }
      }

      // ---- row max: tree + 1 half-swap
      float m8[8];
#pragma unroll
      for (int r = 0; r < 8; ++r)
        m8[r] = fmaxf(fmaxf(s0[r], s0[r + 8]), fmaxf(s1[r], s1[r + 8]));
      float m4a = fmaxf(m8[0], m8[4]), m4b = fmaxf(m8[1], m8[5]);
      float m4c = fmaxf(m8[2], m8[6]), m4d = fmaxf(m8[3], m8[7]);
      const float mloc = fmaxf(fmaxf(m4a, m4b), fmaxf(m4c, m4d));
      const float mt = fmaxf(mloc, __shfl_xor(mloc, 32));

      // ---- defer-max rescale (wave-uniform trigger)
      if (!__all(mt <= m_i + 8.0f)) {
        const float mn = fmaxf(m_i, mt);
        const float al = EX2(m_i - mn);
        l_i *= al;
#pragma unroll
        for (int r = 0; r < 16; ++r) {
          const int qi = (r & 3) + 8 * (r >> 2) + 4 * hi;
          const float a2 = __shfl(al, qi);
          acc0[r] *= a2;
          acc1[r] *= a2;
        }
        m_i = mn;
      }

      // ---- p = 2^(s - m_i), row sum
      float sl2 = 0.f;
#pragma unroll
      for (int r = 0; r < 16; ++r) { s0[r] = EX2(s0[r] - m_i); sl2 += s0[r]; }
#pragma unroll
      for (int r = 0; r < 16; ++r) { s1[r] = EX2(s1[r] - m_i); sl2 += s1[r]; }
      l_i += sl2 + __shfl_xor(sl2, 32);

      // ---- in-register P -> PV A-fragments (16 pack + 16 swap + selects)
      unsigned W0[2][4], W1[2][4], X0[2][4], X1[2][4];
#pragma unroll
      for (int a = 0; a < 2; ++a)
#pragma unroll
        for (int m = 0; m < 4; ++m) {
          W0[a][m] = pk2bf(s0[8 * a + 2 * m], s0[8 * a + 2 * m + 1]);
          W1[a][m] = pk2bf(s1[8 * a + 2 * m], s1[8 * a + 2 * m + 1]);
        }
#pragma unroll
      for (int a = 0; a < 2; ++a)
#pragma unroll
        for (int m = 0; m < 4; ++m) {
          X0[a][m] = __shfl_xor((int)W0[a][m], 32);
          X1[a][m] = __shfl_xor((int)W1[a][m], 32);
        }

      __builtin_amdgcn_s_setprio(1);
#pragma unroll
      for (int ks = 0; ks < 4; ++ks) {
        const int a = ks & 1;
        union { bf16x8 v; unsigned u[4]; } pf;
        if (ks < 2) {
          pf.u[0] = hi ? X0[a][2] : W0[a][0];
          pf.u[1] = hi ? X0[a][3] : W0[a][1];
          pf.u[2] = hi ? W0[a][2] : X0[a][0];
          pf.u[3] = hi ? W0[a][3] : X0[a][1];
        } else {
          pf.u[0] = hi ? X1[a][2] : W1[a][0];
          pf.u[1] = hi ? X1[a][3] : W1[a][1];
          pf.u[2] = hi ? W1[a][2] : X1[a][0];
          pf.u[3] = hi ? W1[a][3] : X1[a][1];
        }
        const int sl = ((2 * ks + hi) ^ swz) * 8;
        const bf16x8 v0 = *(const bf16x8*)&Vtc[q5][sl];
        const bf16x8 v1 = *(const bf16x8*)&Vtc[32 + q5][sl];
        acc0 = __builtin_amdgcn_mfma_f32_32x32x16_bf16(pf.v, v0, acc0, 0, 0, 0);
        acc1 = __builtin_amdgcn_mfma_f32_32x32x16_bf16(pf.v, v1, acc1, 0, 0, 0);
      }
      __builtin_amdgcn_s_setprio(0);
    }

    asm volatile("s_waitcnt lgkmcnt(0)" ::: "memory");
    __builtin_amdgcn_s_barrier();
  }

  // ---- merge group B into group A (lane-aligned), then store
  __syncthreads();
  float* mf = (float*)smem;                     // [4][64][35] f32 = 35840 B
  const int mbase = (wq * 64 + lane) * 35;
  if (grp == 1) {
#pragma unroll
    for (int r = 0; r < 16; ++r) {
      mf[mbase + r] = acc0[r];
      mf[mbase + 16 + r] = acc1[r];
    }
    mf[mbase + 32] = m_i;
    mf[mbase + 33] = l_i;
  }
  __syncthreads();
  if (grp == 0) {
    const float mB = mf[mbase + 32], lB = mf[mbase + 33];
    const float mn = fmaxf(m_i, mB);
    const float fA = EX2(m_i - mn), fB = EX2(mB - mn);
    const float l = l_i * fA + lB * fB;
    const float inv = 1.0f / l;
    short (*tr)[72] = (short(*)[72])(smem + 36864 + wq * 4608);
#pragma unroll
    for (int r = 0; r < 16; ++r) {
      const int qi = (r & 3) + 8 * (r >> 2) + 4 * hi;
      const float fAq = __shfl(fA, qi);
      const float fBq = __shfl(fB, qi);
      const float ivq = __shfl(inv, qi);
      tr[qi][q5] = f2bf((acc0[r] * fAq + mf[mbase + r] * fBq) * ivq);
      tr[qi][32 + q5] = f2bf((acc1[r] * fAq + mf[mbase + 16 + r] * fBq) * ivq);
    }
    asm volatile("s_waitcnt lgkmcnt(0)" ::: "memory");
    const int rr = lane >> 1;
    const int cb = (lane & 1) * 32;
    short* dst =
        Ow + ((size_t)(b * S_LEN + qb + wq * 32 + rr)) * DMODEL + h * DKEY + cb;
#pragma unroll
    for (int i = 0; i < 4; ++i) {
      const bf16x8 o = *(const bf16x8*)&tr[rr][cb + i * 8];
      *(bf16x8*)&dst[i * 8] = o;
    }
  }
}

// ---------------------------------------------------------------------------
// Kernel 3: output projection. 1 block/CU -> 4-deep ring hides HBM latency.
// ---------------------------------------------------------------------------
__global__ __launch_bounds__(256) void gemm_out(
    const short* __restrict__ A, const short* __restrict__ Wz,
    const float* __restrict__ bias, float* __restrict__ out) {
  __shared__ char smem[65536];   // 4 ring buffers x (A 8KB + B 8KB)

  const int m0 = blockIdx.x * 128, n0 = blockIdx.y * 128;
  const int t = threadIdx.x;
  const int lane = t & 63;
  const int w = t >> 6;
  const int quad = lane >> 4;
  const int l15 = lane & 15;
  const int wr = (w >> 1) * 64, wc = (w & 1) * 64;
  const int rswz = (quad ^ ((l15 >> 1) & 3)) * 8;

  const short* Abase = A + (size_t)m0 * DMODEL;
  const short* Bbase = Wz + (size_t)n0 * DMODEL;

  f32x4 acc[4][4] = {};

#pragma unroll
  for (int p = 0; p < 3; ++p) {
    stage_tile32(Abase + p * 32, (short(*)[32])(smem + p * 16384), w, lane);
    stage_tile32(Bbase + p * 32, (short(*)[32])(smem + p * 16384 + 8192), w, lane);
  }

  unsigned o0 = 0, o1 = 16384, o2 = 32768, o3 = 49152;
  for (int it = 0; it < 32; ++it) {
    if (it < 29) {
      const int kt = (it + 3) * 32;
      stage_tile32(Abase + kt, (short(*)[32])(smem + o3), w, lane);
      stage_tile32(Bbase + kt, (short(*)[32])(smem + o3 + 8192), w, lane);
    }
    if (it < 29)       asm volatile("s_waitcnt vmcnt(12)" ::: "memory");
    else if (it == 29) asm volatile("s_waitcnt vmcnt(8)" ::: "memory");
    else if (it == 30) asm volatile("s_waitcnt vmcnt(4)" ::: "memory");
    else               asm volatile("s_waitcnt vmcnt(0)" ::: "memory");
    __builtin_amdgcn_s_barrier();
    short (*As)[32] = (short(*)[32])(smem + o0);
    short (*Bs)[32] = (short(*)[32])(smem + o0 + 8192);
    bf16x8 bf[4], af[4];
#pragma unroll
    for (int nj = 0; nj < 4; ++nj)
      bf[nj] = *(const bf16x8*)&Bs[wc + nj * 16 + l15][rswz];
#pragma unroll
    for (int mi = 0; mi < 4; ++mi)
      af[mi] = *(const bf16x8*)&As[wr + mi * 16 + l15][rswz];
#pragma unroll
    for (int mi = 0; mi < 4; ++mi)
#pragma unroll
      for (int nj = 0; nj < 4; ++nj)
        acc[mi][nj] =
            __builtin_amdgcn_mfma_f32_16x16x32_bf16(af[mi], bf[nj], acc[mi][nj], 0, 0, 0);
    asm volatile("s_waitcnt lgkmcnt(0)" ::: "memory");
    __builtin_amdgcn_s_barrier();
    const unsigned tmp = o0; o0 = o1; o1 = o2; o2 = o3; o3 = tmp;
  }
#pragma unroll
  for (int nj = 0; nj < 4; ++nj) {
    const int n = n0 + wc + nj * 16 + l15;
    const float bval = bias[n];
#pragma unroll
    for (int ti = 0; ti < 4; ++ti)
#pragma unroll
      for (int r = 0; r < 4; ++r) {
        const int m = m0 + wr + ti * 16 + quad * 4 + r;
        out[(size_t)m * DMODEL + n] = acc[ti][nj][r] + bval;
      }
  }
}

// ---------------------------------------------------------------------------
extern "C" void kernel_launch(void* const* d_in, const int* in_sizes, int n_in,
                              void* d_out, int out_size, void* d_ws,
                              size_t ws_size, hipStream_t stream) {
  const float* q      = (const float*)d_in[0];
  const float* k      = (const float*)d_in[1];
  const float* v      = (const float*)d_in[2];
  const float* rope   = (const float*)d_in[3];
  const float* v_mask = (const float*)d_in[5];
  const float* Wq = (const float*)d_in[6];
  const float* bq = (const float*)d_in[7];
  const float* Wk = (const float*)d_in[8];
  const float* bk = (const float*)d_in[9];
  const float* Wv = (const float*)d_in[10];
  const float* bv = (const float*)d_in[11];
  const float* Wo = (const float*)d_in[12];
  const float* bo = (const float*)d_in[13];
  float* out = (float*)d_out;

  short* ws = (short*)d_ws;
  short* Qw = ws;                  // [bh][s][dk] bf16, 8 MB
  short* Kw = ws + 4194304;        // [bh][s][dk] bf16, 8 MB
  short* Vw = ws + 8388608;        // [bh][dk][s] bf16, 8 MB
  short* Ow = ws + 12582912;       // [b][s][dmodel] bf16, 8 MB
  short* Wt = ws + 16777216;       // 4x [n][k] bf16, 8 MB
  short* Xb = ws + 20971520;       // 3x [m][k] bf16, 24 MB  (total 64 MB)

  convert_x<<<dim3(4096, 3), 256, 0, stream>>>(q, k, v, Xb);
  convert_w<<<dim3(16, 16, 4), 256, 0, stream>>>(Wq, Wk, Wv, Wo, Wt);
  gemm_qkv<<<dim3(32, 8, 3), 256, 0, stream>>>(Xb, Wt, bq, bk, bv, rope,
                                               Qw, Kw, Vw);
  attn_kernel<<<dim3(16, 32), 512, 0, stream>>>(Qw, Kw, Vw, v_mask, Ow);
  gemm_out<<<dim3(32, 8), 256, 0, stream>>>(Ow, Wt + 3145728, bo, out);
}